// Round 1
// baseline (6043.851 us; speedup 1.0000x reference)
//
#include <hip/hip_runtime.h>
#include <hip/hip_bf16.h>

#define VOCAB 50000
#define EDIM 256
#define NF 128
#define KS 3
#define HID 128
#define NPATH 128
#define LSEQ 512
#define TCONV 510
#define TPOOL 509

typedef unsigned int uint32;

__device__ __forceinline__ uint32 bf16r(float f) {
  uint32 u = __float_as_uint(f);
  return (u + 0x7fffu + ((u >> 16) & 1u)) >> 16;   // round-to-nearest-even bf16
}
__device__ __forceinline__ uint32 pack2(float a, float b) {
  return bf16r(a) | (bf16r(b) << 16);
}
__device__ __forceinline__ float blo(uint32 w) { return __uint_as_float(w << 16); }
__device__ __forceinline__ float bhi(uint32 w) { return __uint_as_float(w & 0xffff0000u); }

__device__ __forceinline__ float sigf(float x) { return 1.f / (1.f + __expf(-x)); }
__device__ __forceinline__ float tanhf_(float x) {
  float e = __expf(2.f * x);
  return (e - 1.f) / (e + 1.f);
}

// ---------------------------------------------------------------- init:
// transpose conv weights to [e*3+k][f] for coalesced loads; u0 = emb_B[query]
__global__ void init_kernel(const float* __restrict__ conv_w,
                            const float* __restrict__ embB,
                            const int* __restrict__ query,
                            float* __restrict__ w_t, float* __restrict__ u_buf) {
  int idx = blockIdx.x * 256 + threadIdx.x;
  if (idx < EDIM * KS * NF) {
    int ek = idx >> 7, f = idx & (NF - 1);
    w_t[idx] = conv_w[f * (EDIM * KS) + ek];
  } else if (idx < EDIM * KS * NF + EDIM) {
    int i = idx - EDIM * KS * NF;
    u_buf[i] = embB[(size_t)query[0] * EDIM + i];
  }
}

// ---------------------------------------------------------------- conv:
// fused embed gather + conv1d(K=3,VALID) + bias + relu + maxpool(2,stride1)
// block = (t-tile of 32 pooled outputs, path). 256 thr: f = tid&127, th = tid>>7.
__global__ __launch_bounds__(256) void conv_kernel(
    const int* __restrict__ path, const float* __restrict__ embA,
    const float* __restrict__ w_t, const float* __restrict__ conv_b,
    float* __restrict__ pooled) {
  __shared__ float xs[35 * EDIM];
  int t0 = blockIdx.x * 32;
  int p = blockIdx.y;
  const int* prow = path + p * LSEQ;
  for (int tok = 0; tok < 35; ++tok) {
    int tt = t0 + tok;
    float v = 0.f;
    if (tt < LSEQ) v = embA[(size_t)prow[tt] * EDIM + threadIdx.x];
    xs[tok * EDIM + threadIdx.x] = v;
  }
  __syncthreads();
  int f = threadIdx.x & (NF - 1), th = threadIdx.x >> 7;
  float b = conv_b[f];
  float acc[17];
#pragma unroll
  for (int i = 0; i < 17; ++i) acc[i] = b;
  for (int e = 0; e < EDIM; ++e) {
    float xv[19];
#pragma unroll
    for (int j = 0; j < 19; ++j) xv[j] = xs[(th * 16 + j) * EDIM + e];  // broadcast
#pragma unroll
    for (int k = 0; k < KS; ++k) {
      float wv = w_t[(e * KS + k) * NF + f];  // coalesced, L2-resident (393KB)
#pragma unroll
      for (int i = 0; i < 17; ++i) acc[i] += wv * xv[i + k];
    }
  }
#pragma unroll
  for (int i = 0; i < 16; ++i) {
    int t = t0 + th * 16 + i;
    if (t < TPOOL) {
      float v = fmaxf(fmaxf(acc[i], 0.f), fmaxf(acc[i + 1], 0.f));
      pooled[((size_t)p * TPOOL + t) * NF + f] = v;
    }
  }
}

// ---------------------------------------------------------------- lstm:
// one block per (path, direction). 512 thr, thread g owns gate g; its w_ih/w_hh
// rows live in VGPRs as packed bf16 (128 regs). x,h broadcast from LDS, fp32 acc.
__global__ __launch_bounds__(512) void lstm_kernel(
    const float* __restrict__ pooled,
    const float* __restrict__ w_ih_f, const float* __restrict__ w_hh_f,
    const float* __restrict__ b_ih_f, const float* __restrict__ b_hh_f,
    const float* __restrict__ w_ih_b, const float* __restrict__ w_hh_b,
    const float* __restrict__ b_ih_b, const float* __restrict__ b_hh_b,
    float* __restrict__ context) {
  __shared__ __align__(16) float x_l[HID];
  __shared__ __align__(16) float h_l[HID];
  __shared__ float g_l[4 * HID];
  int p = blockIdx.x >> 1, d = blockIdx.x & 1;
  const float* w_ih = d ? w_ih_b : w_ih_f;
  const float* w_hh = d ? w_hh_b : w_hh_f;
  const float* b_ih = d ? b_ih_b : b_ih_f;
  const float* b_hh = d ? b_hh_b : b_hh_f;
  int g = threadIdx.x;
  float bias = b_ih[g] + b_hh[g];
  uint32 wih[64], whh[64];
#pragma unroll
  for (int j = 0; j < 32; ++j) {
    float4 a = *(const float4*)(w_ih + g * HID + 4 * j);
    wih[2 * j] = pack2(a.x, a.y);
    wih[2 * j + 1] = pack2(a.z, a.w);
    float4 b4 = *(const float4*)(w_hh + g * HID + 4 * j);
    whh[2 * j] = pack2(b4.x, b4.y);
    whh[2 * j + 1] = pack2(b4.z, b4.w);
  }
  float c = 0.f, h = 0.f;
  if (g < HID) h_l[g] = 0.f;
  const float* prow = pooled + (size_t)p * TPOOL * NF;
  for (int t = 0; t < TPOOL; ++t) {
    if (g < HID) {
      int ti = d ? (TPOOL - 1 - t) : t;
      x_l[g] = prow[ti * NF + g];
    }
    __syncthreads();  // x_l staged, h_l from prev step ready
    float a0 = bias, a1 = 0.f, a2 = 0.f, a3 = 0.f;
    const float4* x4 = (const float4*)x_l;
    const float4* h4 = (const float4*)h_l;
#pragma unroll
    for (int j = 0; j < 32; ++j) {
      float4 xv = x4[j];
      uint32 wa = wih[2 * j], wb = wih[2 * j + 1];
      a0 += blo(wa) * xv.x;
      a1 += bhi(wa) * xv.y;
      a2 += blo(wb) * xv.z;
      a3 += bhi(wb) * xv.w;
    }
#pragma unroll
    for (int j = 0; j < 32; ++j) {
      float4 hv = h4[j];
      uint32 wa = whh[2 * j], wb = whh[2 * j + 1];
      a0 += blo(wa) * hv.x;
      a1 += bhi(wa) * hv.y;
      a2 += blo(wb) * hv.z;
      a3 += bhi(wb) * hv.w;
    }
    g_l[g] = (a0 + a1) + (a2 + a3);
    __syncthreads();  // gates complete
    if (g < HID) {
      float gi = g_l[g], gf = g_l[HID + g], gg = g_l[2 * HID + g],
            go = g_l[3 * HID + g];
      c = sigf(gf) * c + sigf(gi) * tanhf_(gg);
      h = sigf(go) * tanhf_(c);
      h_l[g] = h;
    }
  }
  if (g < HID) context[p * 2 * HID + d * HID + g] = h;
}

// ---------------------------------------------------------------- attention
__global__ __launch_bounds__(256) void score_kernel(
    const float* __restrict__ context, const float* __restrict__ u_buf,
    const float* __restrict__ d1_w, const float* __restrict__ d1_b,
    const float* __restrict__ d2_w, const float* __restrict__ d2_b,
    float* __restrict__ scores) {
  __shared__ __align__(16) float cat[2 * EDIM];
  __shared__ float red[4];
  int p = blockIdx.x;
  int i = threadIdx.x;
  cat[i] = context[p * 2 * HID + i];
  cat[EDIM + i] = u_buf[i];
  __syncthreads();
  float acc = d1_b[i];
  const float4* wrow = (const float4*)(d1_w + (size_t)i * 2 * EDIM);
#pragma unroll 8
  for (int j = 0; j < 128; ++j) {
    float4 w4 = wrow[j];
    float4 c4 = *(const float4*)(&cat[4 * j]);
    acc += w4.x * c4.x + w4.y * c4.y + w4.z * c4.z + w4.w * c4.w;
  }
  float v = tanhf_(acc) * d2_w[i];
#pragma unroll
  for (int o = 32; o; o >>= 1) v += __shfl_down(v, o, 64);
  int lane = i & 63, w = i >> 6;
  if (lane == 0) red[w] = v;
  __syncthreads();
  if (i == 0) scores[p] = red[0] + red[1] + red[2] + red[3] + d2_b[0];
}

__global__ __launch_bounds__(256) void reduce_kernel(
    const float* __restrict__ context, const float* __restrict__ d1_w,
    const float* __restrict__ d1_b, const float* __restrict__ d2_w,
    const float* __restrict__ d2_b, const float* __restrict__ scores,
    float* __restrict__ u_buf, float* __restrict__ out, int final_step) {
  __shared__ float al[NPATH];
  __shared__ __align__(16) float uo[2 * EDIM];
  __shared__ float red[4];
  int i = threadIdx.x;
  int lane = i & 63, w = i >> 6;

  // softmax over 128 path scores
  float s = (i < NPATH) ? scores[i] : -1e30f;
  float m = s;
#pragma unroll
  for (int o = 32; o; o >>= 1) m = fmaxf(m, __shfl_down(m, o, 64));
  if (lane == 0) red[w] = m;
  __syncthreads();
  m = fmaxf(fmaxf(red[0], red[1]), fmaxf(red[2], red[3]));
  __syncthreads();
  float e = (i < NPATH) ? __expf(s - m) : 0.f;
  float t = e;
#pragma unroll
  for (int o = 32; o; o >>= 1) t += __shfl_down(t, o, 64);
  if (lane == 0) red[w] = t;
  __syncthreads();
  float sum = red[0] + red[1] + red[2] + red[3];
  if (i < NPATH) al[i] = e / sum;
  __syncthreads();

  // o = sum_p alpha[p] * context[p]  (i in 0..255)
  float o_i = 0.f;
  for (int p = 0; p < NPATH; ++p) o_i += al[p] * context[p * 2 * HID + i];
  uo[i] = u_buf[i];
  uo[EDIM + i] = o_i;
  __syncthreads();

  // u_new = [u;o] @ d1_w.T + d1_b
  float un = d1_b[i];
  const float4* wrow = (const float4*)(d1_w + (size_t)i * 2 * EDIM);
#pragma unroll 8
  for (int j = 0; j < 128; ++j) {
    float4 w4 = wrow[j];
    float4 c4 = *(const float4*)(&uo[4 * j]);
    un += w4.x * c4.x + w4.y * c4.y + w4.z * c4.z + w4.w * c4.w;
  }
  if (!final_step) {
    u_buf[i] = un;
  } else {
    float v = fmaxf(un, 0.f) * d2_w[i];
#pragma unroll
    for (int o = 32; o; o >>= 1) v += __shfl_down(v, o, 64);
    if (lane == 0) red[w] = v;
    __syncthreads();
    if (i == 0) {
      float tot = red[0] + red[1] + red[2] + red[3] + d2_b[0];
      out[0] = 1.f / (1.f + __expf(-tot));
    }
  }
}

// ----------------------------------------------------------------
extern "C" void kernel_launch(void* const* d_in, const int* in_sizes, int n_in,
                              void* d_out, int out_size, void* d_ws, size_t ws_size,
                              hipStream_t stream) {
  const int* path = (const int*)d_in[0];
  const int* query = (const int*)d_in[1];
  const float* embA = (const float*)d_in[2];
  const float* embB = (const float*)d_in[3];
  const float* conv_w = (const float*)d_in[4];
  const float* conv_b = (const float*)d_in[5];
  const float* w_ih_f = (const float*)d_in[6];
  const float* w_hh_f = (const float*)d_in[7];
  const float* b_ih_f = (const float*)d_in[8];
  const float* b_hh_f = (const float*)d_in[9];
  const float* w_ih_b = (const float*)d_in[10];
  const float* w_hh_b = (const float*)d_in[11];
  const float* b_ih_b = (const float*)d_in[12];
  const float* b_hh_b = (const float*)d_in[13];
  const float* d1_w = (const float*)d_in[14];
  const float* d1_b = (const float*)d_in[15];
  const float* d2_w = (const float*)d_in[16];
  const float* d2_b = (const float*)d_in[17];
  float* out = (float*)d_out;

  float* ws = (float*)d_ws;
  float* pooled = ws;                                     // 128*509*128
  float* w_t = pooled + (size_t)NPATH * TPOOL * NF;       // 768*128
  float* context = w_t + EDIM * KS * NF;                  // 128*256
  float* scores = context + NPATH * 2 * HID;              // 128
  float* u_buf = scores + NPATH;                          // 256

  init_kernel<<<(EDIM * KS * NF + EDIM + 255) / 256, 256, 0, stream>>>(
      conv_w, embB, query, w_t, u_buf);
  conv_kernel<<<dim3(16, NPATH), 256, 0, stream>>>(path, embA, w_t, conv_b,
                                                   pooled);
  lstm_kernel<<<256, 512, 0, stream>>>(pooled, w_ih_f, w_hh_f, b_ih_f, b_hh_f,
                                       w_ih_b, w_hh_b, b_ih_b, b_hh_b, context);
  score_kernel<<<NPATH, 256, 0, stream>>>(context, u_buf, d1_w, d1_b, d2_w,
                                          d2_b, scores);
  reduce_kernel<<<1, 256, 0, stream>>>(context, d1_w, d1_b, d2_w, d2_b, scores,
                                       u_buf, out, 0);
  score_kernel<<<NPATH, 256, 0, stream>>>(context, u_buf, d1_w, d1_b, d2_w,
                                          d2_b, scores);
  reduce_kernel<<<1, 256, 0, stream>>>(context, d1_w, d1_b, d2_w, d2_b, scores,
                                       u_buf, out, 1);
}

// Round 6
// 5437.481 us; speedup vs baseline: 1.1115x; 1.1115x over previous
//
#include <hip/hip_runtime.h>
#include <hip/hip_bf16.h>

#define VOCAB 50000
#define EDIM 256
#define NF 128
#define KS 3
#define HID 128
#define NPATH 128
#define LSEQ 512
#define TCONV 510
#define TPOOL 509

typedef unsigned int uint32;

__device__ __forceinline__ uint32 bf16r(float f) {
  uint32 u = __float_as_uint(f);
  return (u + 0x7fffu + ((u >> 16) & 1u)) >> 16;   // round-to-nearest-even bf16
}
__device__ __forceinline__ uint32 pack2(float a, float b) {
  return bf16r(a) | (bf16r(b) << 16);
}
__device__ __forceinline__ float blo(uint32 w) { return __uint_as_float(w << 16); }
__device__ __forceinline__ float bhi(uint32 w) { return __uint_as_float(w & 0xffff0000u); }

__device__ __forceinline__ float sigf(float x) { return 1.f / (1.f + __expf(-x)); }
__device__ __forceinline__ float tanhf_(float x) {
  float e = __expf(2.f * x);
  return (e - 1.f) / (e + 1.f);
}

// ---------------------------------------------------------------- init:
// transpose conv weights to [e*3+k][f] for coalesced loads; u0 = emb_B[query]
__global__ void init_kernel(const float* __restrict__ conv_w,
                            const float* __restrict__ embB,
                            const int* __restrict__ query,
                            float* __restrict__ w_t, float* __restrict__ u_buf) {
  int idx = blockIdx.x * 256 + threadIdx.x;
  if (idx < EDIM * KS * NF) {
    int ek = idx >> 7, f = idx & (NF - 1);
    w_t[idx] = conv_w[f * (EDIM * KS) + ek];
  } else if (idx < EDIM * KS * NF + EDIM) {
    int i = idx - EDIM * KS * NF;
    u_buf[i] = embB[(size_t)query[0] * EDIM + i];
  }
}

// ---------------------------------------------------------------- conv:
// fused embed gather + conv1d(K=3,VALID) + bias + relu + maxpool(2,stride1)
// block = (t-tile of 32 pooled outputs, path). 256 thr: f = tid&127, th = tid>>7.
__global__ __launch_bounds__(256) void conv_kernel(
    const int* __restrict__ path, const float* __restrict__ embA,
    const float* __restrict__ w_t, const float* __restrict__ conv_b,
    float* __restrict__ pooled) {
  __shared__ float xs[35 * EDIM];
  int t0 = blockIdx.x * 32;
  int p = blockIdx.y;
  const int* prow = path + p * LSEQ;
  for (int tok = 0; tok < 35; ++tok) {
    int tt = t0 + tok;
    float v = 0.f;
    if (tt < LSEQ) v = embA[(size_t)prow[tt] * EDIM + threadIdx.x];
    xs[tok * EDIM + threadIdx.x] = v;
  }
  __syncthreads();
  int f = threadIdx.x & (NF - 1), th = threadIdx.x >> 7;
  float b = conv_b[f];
  float acc[17];
#pragma unroll
  for (int i = 0; i < 17; ++i) acc[i] = b;
  for (int e = 0; e < EDIM; ++e) {
    float xv[19];
#pragma unroll
    for (int j = 0; j < 19; ++j) xv[j] = xs[(th * 16 + j) * EDIM + e];  // broadcast
#pragma unroll
    for (int k = 0; k < KS; ++k) {
      float wv = w_t[(e * KS + k) * NF + f];  // coalesced, L2-resident (393KB)
#pragma unroll
      for (int i = 0; i < 17; ++i) acc[i] += wv * xv[i + k];
    }
  }
#pragma unroll
  for (int i = 0; i < 16; ++i) {
    int t = t0 + th * 16 + i;
    if (t < TPOOL) {
      float v = fmaxf(fmaxf(acc[i], 0.f), fmaxf(acc[i + 1], 0.f));
      pooled[((size_t)p * TPOOL + t) * NF + f] = v;
    }
  }
}

// ---------------------------------------------------------------- lstm:
// one block per (path, direction). 512 thr, thread g owns gate g; its w_ih/w_hh
// rows live in VGPRs as packed bf16 (128 regs). x,h broadcast from LDS, fp32 acc.
// __launch_bounds__(512, 2): cap = 256 VGPR (2 waves/EU) -> NO spill of the
// 128 weight regs (round 1: default cap 128 spilled half the weights to
// scratch -> 3.0 GB HBM refetch/dispatch, VALUBusy 10%).
__global__ __launch_bounds__(512, 2) void lstm_kernel(
    const float* __restrict__ pooled,
    const float* __restrict__ w_ih_f, const float* __restrict__ w_hh_f,
    const float* __restrict__ b_ih_f, const float* __restrict__ b_hh_f,
    const float* __restrict__ w_ih_b, const float* __restrict__ w_hh_b,
    const float* __restrict__ b_ih_b, const float* __restrict__ b_hh_b,
    float* __restrict__ context) {
  __shared__ __align__(16) float x_l[2][HID];   // double-buffered input slice
  __shared__ __align__(16) float h_l[HID];
  __shared__ float g_l[4 * HID];
  int p = blockIdx.x >> 1, d = blockIdx.x & 1;
  const float* w_ih = d ? w_ih_b : w_ih_f;
  const float* w_hh = d ? w_hh_b : w_hh_f;
  const float* b_ih = d ? b_ih_b : b_ih_f;
  const float* b_hh = d ? b_hh_b : b_hh_f;
  int g = threadIdx.x;
  float bias = b_ih[g] + b_hh[g];
  uint32 wih[64], whh[64];
#pragma unroll
  for (int j = 0; j < 32; ++j) {
    float4 a = *(const float4*)(w_ih + g * HID + 4 * j);
    wih[2 * j] = pack2(a.x, a.y);
    wih[2 * j + 1] = pack2(a.z, a.w);
    float4 b4 = *(const float4*)(w_hh + g * HID + 4 * j);
    whh[2 * j] = pack2(b4.x, b4.y);
    whh[2 * j + 1] = pack2(b4.z, b4.w);
  }
  float c = 0.f, h = 0.f;
  const float* prow = pooled + (size_t)p * TPOOL * NF;
  if (g < HID) {
    h_l[g] = 0.f;
    int ti0 = d ? (TPOOL - 1) : 0;
    x_l[0][g] = prow[ti0 * NF + g];
  }
  __syncthreads();
  int cur = 0;
  float xreg = 0.f;
  for (int t = 0; t < TPOOL; ++t) {
    // issue next step's x load early: latency hides under the 256-FMA dot
    if (g < HID && t + 1 < TPOOL) {
      int ti = d ? (TPOOL - 2 - t) : (t + 1);
      xreg = prow[ti * NF + g];
    }
    float a0 = bias, a1 = 0.f, a2 = 0.f, a3 = 0.f;
    const float4* x4 = (const float4*)x_l[cur];
    const float4* h4 = (const float4*)h_l;
#pragma unroll
    for (int j = 0; j < 32; ++j) {
      float4 xv = x4[j];
      uint32 wa = wih[2 * j], wb = wih[2 * j + 1];
      a0 += blo(wa) * xv.x;
      a1 += bhi(wa) * xv.y;
      a2 += blo(wb) * xv.z;
      a3 += bhi(wb) * xv.w;
    }
#pragma unroll
    for (int j = 0; j < 32; ++j) {
      float4 hv = h4[j];
      uint32 wa = whh[2 * j], wb = whh[2 * j + 1];
      a0 += blo(wa) * hv.x;
      a1 += bhi(wa) * hv.y;
      a2 += blo(wb) * hv.z;
      a3 += bhi(wb) * hv.w;
    }
    g_l[g] = (a0 + a1) + (a2 + a3);
    __syncthreads();  // gates complete
    if (g < HID) {
      float gi = g_l[g], gf = g_l[HID + g], gg = g_l[2 * HID + g],
            go = g_l[3 * HID + g];
      c = sigf(gf) * c + sigf(gi) * tanhf_(gg);
      h = sigf(go) * tanhf_(c);
      h_l[g] = h;
      if (t + 1 < TPOOL) x_l[cur ^ 1][g] = xreg;
    }
    __syncthreads();  // h_l / x_l[alt] ready for next step
    cur ^= 1;
  }
  if (g < HID) context[p * 2 * HID + d * HID + g] = h;
}

// ---------------------------------------------------------------- attention
__global__ __launch_bounds__(256) void score_kernel(
    const float* __restrict__ context, const float* __restrict__ u_buf,
    const float* __restrict__ d1_w, const float* __restrict__ d1_b,
    const float* __restrict__ d2_w, const float* __restrict__ d2_b,
    float* __restrict__ scores) {
  __shared__ __align__(16) float cat[2 * EDIM];
  __shared__ float red[4];
  int p = blockIdx.x;
  int i = threadIdx.x;
  cat[i] = context[p * 2 * HID + i];
  cat[EDIM + i] = u_buf[i];
  __syncthreads();
  float acc = d1_b[i];
  const float4* wrow = (const float4*)(d1_w + (size_t)i * 2 * EDIM);
#pragma unroll 8
  for (int j = 0; j < 128; ++j) {
    float4 w4 = wrow[j];
    float4 c4 = *(const float4*)(&cat[4 * j]);
    acc += w4.x * c4.x + w4.y * c4.y + w4.z * c4.z + w4.w * c4.w;
  }
  float v = tanhf_(acc) * d2_w[i];
#pragma unroll
  for (int o = 32; o; o >>= 1) v += __shfl_down(v, o, 64);
  int lane = i & 63, w = i >> 6;
  if (lane == 0) red[w] = v;
  __syncthreads();
  if (i == 0) scores[p] = red[0] + red[1] + red[2] + red[3] + d2_b[0];
}

__global__ __launch_bounds__(256) void reduce_kernel(
    const float* __restrict__ context, const float* __restrict__ d1_w,
    const float* __restrict__ d1_b, const float* __restrict__ d2_w,
    const float* __restrict__ d2_b, const float* __restrict__ scores,
    float* __restrict__ u_buf, float* __restrict__ out, int final_step) {
  __shared__ float al[NPATH];
  __shared__ __align__(16) float uo[2 * EDIM];
  __shared__ float red[4];
  int i = threadIdx.x;
  int lane = i & 63, w = i >> 6;

  // softmax over 128 path scores
  float s = (i < NPATH) ? scores[i] : -1e30f;
  float m = s;
#pragma unroll
  for (int o = 32; o; o >>= 1) m = fmaxf(m, __shfl_down(m, o, 64));
  if (lane == 0) red[w] = m;
  __syncthreads();
  m = fmaxf(fmaxf(red[0], red[1]), fmaxf(red[2], red[3]));
  __syncthreads();
  float e = (i < NPATH) ? __expf(s - m) : 0.f;
  float t = e;
#pragma unroll
  for (int o = 32; o; o >>= 1) t += __shfl_down(t, o, 64);
  if (lane == 0) red[w] = t;
  __syncthreads();
  float sum = red[0] + red[1] + red[2] + red[3];
  if (i < NPATH) al[i] = e / sum;
  __syncthreads();

  // o = sum_p alpha[p] * context[p]  (i in 0..255)
  float o_i = 0.f;
  for (int p = 0; p < NPATH; ++p) o_i += al[p] * context[p * 2 * HID + i];
  uo[i] = u_buf[i];
  uo[EDIM + i] = o_i;
  __syncthreads();

  // u_new = [u;o] @ d1_w.T + d1_b
  float un = d1_b[i];
  const float4* wrow = (const float4*)(d1_w + (size_t)i * 2 * EDIM);
#pragma unroll 8
  for (int j = 0; j < 128; ++j) {
    float4 w4 = wrow[j];
    float4 c4 = *(const float4*)(&uo[4 * j]);
    un += w4.x * c4.x + w4.y * c4.y + w4.z * c4.z + w4.w * c4.w;
  }
  if (!final_step) {
    u_buf[i] = un;
  } else {
    float v = fmaxf(un, 0.f) * d2_w[i];
#pragma unroll
    for (int o = 32; o; o >>= 1) v += __shfl_down(v, o, 64);
    if (lane == 0) red[w] = v;
    __syncthreads();
    if (i == 0) {
      float tot = red[0] + red[1] + red[2] + red[3] + d2_b[0];
      out[0] = 1.f / (1.f + __expf(-tot));
    }
  }
}

// ----------------------------------------------------------------
extern "C" void kernel_launch(void* const* d_in, const int* in_sizes, int n_in,
                              void* d_out, int out_size, void* d_ws, size_t ws_size,
                              hipStream_t stream) {
  const int* path = (const int*)d_in[0];
  const int* query = (const int*)d_in[1];
  const float* embA = (const float*)d_in[2];
  const float* embB = (const float*)d_in[3];
  const float* conv_w = (const float*)d_in[4];
  const float* conv_b = (const float*)d_in[5];
  const float* w_ih_f = (const float*)d_in[6];
  const float* w_hh_f = (const float*)d_in[7];
  const float* b_ih_f = (const float*)d_in[8];
  const float* b_hh_f = (const float*)d_in[9];
  const float* w_ih_b = (const float*)d_in[10];
  const float* w_hh_b = (const float*)d_in[11];
  const float* b_ih_b = (const float*)d_in[12];
  const float* b_hh_b = (const float*)d_in[13];
  const float* d1_w = (const float*)d_in[14];
  const float* d1_b = (const float*)d_in[15];
  const float* d2_w = (const float*)d_in[16];
  const float* d2_b = (const float*)d_in[17];
  float* out = (float*)d_out;

  float* ws = (float*)d_ws;
  float* pooled = ws;                                     // 128*509*128
  float* w_t = pooled + (size_t)NPATH * TPOOL * NF;       // 768*128
  float* context = w_t + EDIM * KS * NF;                  // 128*256
  float* scores = context + NPATH * 2 * HID;              // 128
  float* u_buf = scores + NPATH;                          // 256

  init_kernel<<<(EDIM * KS * NF + EDIM + 255) / 256, 256, 0, stream>>>(
      conv_w, embB, query, w_t, u_buf);
  conv_kernel<<<dim3(16, NPATH), 256, 0, stream>>>(path, embA, w_t, conv_b,
                                                   pooled);
  lstm_kernel<<<256, 512, 0, stream>>>(pooled, w_ih_f, w_hh_f, b_ih_f, b_hh_f,
                                       w_ih_b, w_hh_b, b_ih_b, b_hh_b, context);
  score_kernel<<<NPATH, 256, 0, stream>>>(context, u_buf, d1_w, d1_b, d2_w,
                                          d2_b, scores);
  reduce_kernel<<<1, 256, 0, stream>>>(context, d1_w, d1_b, d2_w, d2_b, scores,
                                       u_buf, out, 0);
  score_kernel<<<NPATH, 256, 0, stream>>>(context, u_buf, d1_w, d1_b, d2_w,
                                          d2_b, scores);
  reduce_kernel<<<1, 256, 0, stream>>>(context, d1_w, d1_b, d2_w, d2_b, scores,
                                       u_buf, out, 1);
}

// Round 7
// 5416.124 us; speedup vs baseline: 1.1159x; 1.0039x over previous
//
#include <hip/hip_runtime.h>
#include <hip/hip_bf16.h>

#define VOCAB 50000
#define EDIM 256
#define NF 128
#define KS 3
#define HID 128
#define NPATH 128
#define LSEQ 512
#define TCONV 510
#define TPOOL 509

typedef unsigned int uint32;

__device__ __forceinline__ uint32 bf16r(float f) {
  uint32 u = __float_as_uint(f);
  return (u + 0x7fffu + ((u >> 16) & 1u)) >> 16;   // round-to-nearest-even bf16
}
__device__ __forceinline__ uint32 pack2(float a, float b) {
  return bf16r(a) | (bf16r(b) << 16);
}
__device__ __forceinline__ float blo(uint32 w) { return __uint_as_float(w << 16); }
__device__ __forceinline__ float bhi(uint32 w) { return __uint_as_float(w & 0xffff0000u); }

__device__ __forceinline__ float sigf(float x) { return 1.f / (1.f + __expf(-x)); }
__device__ __forceinline__ float tanhf_(float x) {
  float e = __expf(2.f * x);
  return (e - 1.f) / (e + 1.f);
}

// ---------------------------------------------------------------- init:
// transpose conv weights to [e*3+k][f] for coalesced loads; u0 = emb_B[query]
__global__ void init_kernel(const float* __restrict__ conv_w,
                            const float* __restrict__ embB,
                            const int* __restrict__ query,
                            float* __restrict__ w_t, float* __restrict__ u_buf) {
  int idx = blockIdx.x * 256 + threadIdx.x;
  if (idx < EDIM * KS * NF) {
    int ek = idx >> 7, f = idx & (NF - 1);
    w_t[idx] = conv_w[f * (EDIM * KS) + ek];
  } else if (idx < EDIM * KS * NF + EDIM) {
    int i = idx - EDIM * KS * NF;
    u_buf[i] = embB[(size_t)query[0] * EDIM + i];
  }
}

// ---------------------------------------------------------------- conv:
// fused embed gather + conv1d(K=3,VALID) + bias + relu + maxpool(2,stride1)
// block = (t-tile of 32 pooled outputs, path). 256 thr: f = tid&127, th = tid>>7.
__global__ __launch_bounds__(256) void conv_kernel(
    const int* __restrict__ path, const float* __restrict__ embA,
    const float* __restrict__ w_t, const float* __restrict__ conv_b,
    float* __restrict__ pooled) {
  __shared__ float xs[35 * EDIM];
  int t0 = blockIdx.x * 32;
  int p = blockIdx.y;
  const int* prow = path + p * LSEQ;
  for (int tok = 0; tok < 35; ++tok) {
    int tt = t0 + tok;
    float v = 0.f;
    if (tt < LSEQ) v = embA[(size_t)prow[tt] * EDIM + threadIdx.x];
    xs[tok * EDIM + threadIdx.x] = v;
  }
  __syncthreads();
  int f = threadIdx.x & (NF - 1), th = threadIdx.x >> 7;
  float b = conv_b[f];
  float acc[17];
#pragma unroll
  for (int i = 0; i < 17; ++i) acc[i] = b;
  for (int e = 0; e < EDIM; ++e) {
    float xv[19];
#pragma unroll
    for (int j = 0; j < 19; ++j) xv[j] = xs[(th * 16 + j) * EDIM + e];  // broadcast
#pragma unroll
    for (int k = 0; k < KS; ++k) {
      float wv = w_t[(e * KS + k) * NF + f];  // coalesced, L2-resident (393KB)
#pragma unroll
      for (int i = 0; i < 17; ++i) acc[i] += wv * xv[i + k];
    }
  }
#pragma unroll
  for (int i = 0; i < 16; ++i) {
    int t = t0 + th * 16 + i;
    if (t < TPOOL) {
      float v = fmaxf(fmaxf(acc[i], 0.f), fmaxf(acc[i + 1], 0.f));
      pooled[((size_t)p * TPOOL + t) * NF + f] = v;
    }
  }
}

// ---------------------------------------------------------------- lstm:
// one block per (path, direction). 512 thr, thread g owns gate g; its w_ih/w_hh
// rows live in VGPRs as packed bf16 (128 regs). x,h broadcast from LDS, fp32 acc.
// __launch_bounds__(512, 1): round-6 evidence showed (512,2) left VGPR_Count
// at exactly 128 = pool(512)/4 waves-per-SIMD, i.e. the 2nd arg behaved as
// min BLOCKS/CU (2 blk * 8 waves = 4 waves/SIMD). With 1: cap >= 256 VGPR
// under either semantics -> the 128 weight regs + working set fit, no spill.
// (Grid is 1 block/CU anyway, so no occupancy loss.)
__global__ __launch_bounds__(512, 1) void lstm_kernel(
    const float* __restrict__ pooled,
    const float* __restrict__ w_ih_f, const float* __restrict__ w_hh_f,
    const float* __restrict__ b_ih_f, const float* __restrict__ b_hh_f,
    const float* __restrict__ w_ih_b, const float* __restrict__ w_hh_b,
    const float* __restrict__ b_ih_b, const float* __restrict__ b_hh_b,
    float* __restrict__ context) {
  __shared__ __align__(16) float x_l[2][HID];   // double-buffered input slice
  __shared__ __align__(16) float h_l[HID];
  __shared__ float g_l[4 * HID];
  int p = blockIdx.x >> 1, d = blockIdx.x & 1;
  const float* w_ih = d ? w_ih_b : w_ih_f;
  const float* w_hh = d ? w_hh_b : w_hh_f;
  const float* b_ih = d ? b_ih_b : b_ih_f;
  const float* b_hh = d ? b_hh_b : b_hh_f;
  int g = threadIdx.x;
  float bias = b_ih[g] + b_hh[g];
  uint32 wih[64], whh[64];
#pragma unroll
  for (int j = 0; j < 32; ++j) {
    float4 a = *(const float4*)(w_ih + g * HID + 4 * j);
    wih[2 * j] = pack2(a.x, a.y);
    wih[2 * j + 1] = pack2(a.z, a.w);
    float4 b4 = *(const float4*)(w_hh + g * HID + 4 * j);
    whh[2 * j] = pack2(b4.x, b4.y);
    whh[2 * j + 1] = pack2(b4.z, b4.w);
  }
  float c = 0.f, h = 0.f;
  const float* prow = pooled + (size_t)p * TPOOL * NF;
  if (g < HID) {
    h_l[g] = 0.f;
    int ti0 = d ? (TPOOL - 1) : 0;
    x_l[0][g] = prow[ti0 * NF + g];
  }
  __syncthreads();
  int cur = 0;
  float xreg = 0.f;
  for (int t = 0; t < TPOOL; ++t) {
    // issue next step's x load early: latency hides under the 256-FMA dot
    if (g < HID && t + 1 < TPOOL) {
      int ti = d ? (TPOOL - 2 - t) : (t + 1);
      xreg = prow[ti * NF + g];
    }
    float a0 = bias, a1 = 0.f, a2 = 0.f, a3 = 0.f;
    const float4* x4 = (const float4*)x_l[cur];
    const float4* h4 = (const float4*)h_l;
#pragma unroll
    for (int j = 0; j < 32; ++j) {
      float4 xv = x4[j];
      uint32 wa = wih[2 * j], wb = wih[2 * j + 1];
      a0 += blo(wa) * xv.x;
      a1 += bhi(wa) * xv.y;
      a2 += blo(wb) * xv.z;
      a3 += bhi(wb) * xv.w;
    }
#pragma unroll
    for (int j = 0; j < 32; ++j) {
      float4 hv = h4[j];
      uint32 wa = whh[2 * j], wb = whh[2 * j + 1];
      a0 += blo(wa) * hv.x;
      a1 += bhi(wa) * hv.y;
      a2 += blo(wb) * hv.z;
      a3 += bhi(wb) * hv.w;
    }
    g_l[g] = (a0 + a1) + (a2 + a3);
    __syncthreads();  // gates complete
    if (g < HID) {
      float gi = g_l[g], gf = g_l[HID + g], gg = g_l[2 * HID + g],
            go = g_l[3 * HID + g];
      c = sigf(gf) * c + sigf(gi) * tanhf_(gg);
      h = sigf(go) * tanhf_(c);
      h_l[g] = h;
      if (t + 1 < TPOOL) x_l[cur ^ 1][g] = xreg;
    }
    __syncthreads();  // h_l / x_l[alt] ready for next step
    cur ^= 1;
  }
  if (g < HID) context[p * 2 * HID + d * HID + g] = h;
}

// ---------------------------------------------------------------- attention
__global__ __launch_bounds__(256) void score_kernel(
    const float* __restrict__ context, const float* __restrict__ u_buf,
    const float* __restrict__ d1_w, const float* __restrict__ d1_b,
    const float* __restrict__ d2_w, const float* __restrict__ d2_b,
    float* __restrict__ scores) {
  __shared__ __align__(16) float cat[2 * EDIM];
  __shared__ float red[4];
  int p = blockIdx.x;
  int i = threadIdx.x;
  cat[i] = context[p * 2 * HID + i];
  cat[EDIM + i] = u_buf[i];
  __syncthreads();
  float acc = d1_b[i];
  const float4* wrow = (const float4*)(d1_w + (size_t)i * 2 * EDIM);
#pragma unroll 8
  for (int j = 0; j < 128; ++j) {
    float4 w4 = wrow[j];
    float4 c4 = *(const float4*)(&cat[4 * j]);
    acc += w4.x * c4.x + w4.y * c4.y + w4.z * c4.z + w4.w * c4.w;
  }
  float v = tanhf_(acc) * d2_w[i];
#pragma unroll
  for (int o = 32; o; o >>= 1) v += __shfl_down(v, o, 64);
  int lane = i & 63, w = i >> 6;
  if (lane == 0) red[w] = v;
  __syncthreads();
  if (i == 0) scores[p] = red[0] + red[1] + red[2] + red[3] + d2_b[0];
}

__global__ __launch_bounds__(256) void reduce_kernel(
    const float* __restrict__ context, const float* __restrict__ d1_w,
    const float* __restrict__ d1_b, const float* __restrict__ d2_w,
    const float* __restrict__ d2_b, const float* __restrict__ scores,
    float* __restrict__ u_buf, float* __restrict__ out, int final_step) {
  __shared__ float al[NPATH];
  __shared__ __align__(16) float uo[2 * EDIM];
  __shared__ float red[4];
  int i = threadIdx.x;
  int lane = i & 63, w = i >> 6;

  // softmax over 128 path scores
  float s = (i < NPATH) ? scores[i] : -1e30f;
  float m = s;
#pragma unroll
  for (int o = 32; o; o >>= 1) m = fmaxf(m, __shfl_down(m, o, 64));
  if (lane == 0) red[w] = m;
  __syncthreads();
  m = fmaxf(fmaxf(red[0], red[1]), fmaxf(red[2], red[3]));
  __syncthreads();
  float e = (i < NPATH) ? __expf(s - m) : 0.f;
  float t = e;
#pragma unroll
  for (int o = 32; o; o >>= 1) t += __shfl_down(t, o, 64);
  if (lane == 0) red[w] = t;
  __syncthreads();
  float sum = red[0] + red[1] + red[2] + red[3];
  if (i < NPATH) al[i] = e / sum;
  __syncthreads();

  // o = sum_p alpha[p] * context[p]  (i in 0..255)
  float o_i = 0.f;
  for (int p = 0; p < NPATH; ++p) o_i += al[p] * context[p * 2 * HID + i];
  uo[i] = u_buf[i];
  uo[EDIM + i] = o_i;
  __syncthreads();

  // u_new = [u;o] @ d1_w.T + d1_b
  float un = d1_b[i];
  const float4* wrow = (const float4*)(d1_w + (size_t)i * 2 * EDIM);
#pragma unroll 8
  for (int j = 0; j < 128; ++j) {
    float4 w4 = wrow[j];
    float4 c4 = *(const float4*)(&uo[4 * j]);
    un += w4.x * c4.x + w4.y * c4.y + w4.z * c4.z + w4.w * c4.w;
  }
  if (!final_step) {
    u_buf[i] = un;
  } else {
    float v = fmaxf(un, 0.f) * d2_w[i];
#pragma unroll
    for (int o = 32; o; o >>= 1) v += __shfl_down(v, o, 64);
    if (lane == 0) red[w] = v;
    __syncthreads();
    if (i == 0) {
      float tot = red[0] + red[1] + red[2] + red[3] + d2_b[0];
      out[0] = 1.f / (1.f + __expf(-tot));
    }
  }
}

// ----------------------------------------------------------------
extern "C" void kernel_launch(void* const* d_in, const int* in_sizes, int n_in,
                              void* d_out, int out_size, void* d_ws, size_t ws_size,
                              hipStream_t stream) {
  const int* path = (const int*)d_in[0];
  const int* query = (const int*)d_in[1];
  const float* embA = (const float*)d_in[2];
  const float* embB = (const float*)d_in[3];
  const float* conv_w = (const float*)d_in[4];
  const float* conv_b = (const float*)d_in[5];
  const float* w_ih_f = (const float*)d_in[6];
  const float* w_hh_f = (const float*)d_in[7];
  const float* b_ih_f = (const float*)d_in[8];
  const float* b_hh_f = (const float*)d_in[9];
  const float* w_ih_b = (const float*)d_in[10];
  const float* w_hh_b = (const float*)d_in[11];
  const float* b_ih_b = (const float*)d_in[12];
  const float* b_hh_b = (const float*)d_in[13];
  const float* d1_w = (const float*)d_in[14];
  const float* d1_b = (const float*)d_in[15];
  const float* d2_w = (const float*)d_in[16];
  const float* d2_b = (const float*)d_in[17];
  float* out = (float*)d_out;

  float* ws = (float*)d_ws;
  float* pooled = ws;                                     // 128*509*128
  float* w_t = pooled + (size_t)NPATH * TPOOL * NF;       // 768*128
  float* context = w_t + EDIM * KS * NF;                  // 128*256
  float* scores = context + NPATH * 2 * HID;              // 128
  float* u_buf = scores + NPATH;                          // 256

  init_kernel<<<(EDIM * KS * NF + EDIM + 255) / 256, 256, 0, stream>>>(
      conv_w, embB, query, w_t, u_buf);
  conv_kernel<<<dim3(16, NPATH), 256, 0, stream>>>(path, embA, w_t, conv_b,
                                                   pooled);
  lstm_kernel<<<256, 512, 0, stream>>>(pooled, w_ih_f, w_hh_f, b_ih_f, b_hh_f,
                                       w_ih_b, w_hh_b, b_ih_b, b_hh_b, context);
  score_kernel<<<NPATH, 256, 0, stream>>>(context, u_buf, d1_w, d1_b, d2_w,
                                          d2_b, scores);
  reduce_kernel<<<1, 256, 0, stream>>>(context, d1_w, d1_b, d2_w, d2_b, scores,
                                       u_buf, out, 0);
  score_kernel<<<NPATH, 256, 0, stream>>>(context, u_buf, d1_w, d1_b, d2_w,
                                          d2_b, scores);
  reduce_kernel<<<1, 256, 0, stream>>>(context, d1_w, d1_b, d2_w, d2_b, scores,
                                       u_buf, out, 1);
}